// Round 1
// baseline (775.963 us; speedup 1.0000x reference)
//
#include <hip/hip_runtime.h>

#define DIM 256

// One 64-lane wave per edge. Lane l holds float4 covering elements [4l, 4l+4).
// score = 0.5 * sum_k r[k] * h[k] * t[(k+128) mod 256]  (fwd/bwd halves fused)
__global__ void __launch_bounds__(256) simple_score_kernel(
    const float* __restrict__ node_emb,
    const float* __restrict__ rel_emb,
    const int* __restrict__ src,
    const int* __restrict__ dst,
    float* __restrict__ out,
    int n_edges)
{
    const int wave = (int)((blockIdx.x * (unsigned)blockDim.x + threadIdx.x) >> 6);
    const int lane = (int)(threadIdx.x & 63u);
    if (wave >= n_edges) return;

    const long long s = src[wave];
    const long long d = dst[wave];

    const float4* __restrict__ h4 = (const float4*)(node_emb + s * DIM);
    const float4* __restrict__ t4 = (const float4*)(node_emb + d * DIM);
    const float4* __restrict__ r4 = (const float4*)(rel_emb + (long long)wave * DIM);

    const float4 h = h4[lane];
    const float4 r = r4[lane];
    // t rotated by 128 floats = 32 float4s (mod 64)
    const float4 t = t4[(lane + 32) & 63];

    float p = h.x * r.x * t.x;
    p = fmaf(h.y * r.y, t.y, p);
    p = fmaf(h.z * r.z, t.z, p);
    p = fmaf(h.w * r.w, t.w, p);

    // 64-lane wave reduction
    #pragma unroll
    for (int off = 32; off > 0; off >>= 1)
        p += __shfl_down(p, off, 64);

    if (lane == 0) {
        float sc = 0.5f * p;
        sc = fminf(fmaxf(sc, -20.0f), 20.0f);
        out[wave] = sc;
    }
}

extern "C" void kernel_launch(void* const* d_in, const int* in_sizes, int n_in,
                              void* d_out, int out_size, void* d_ws, size_t ws_size,
                              hipStream_t stream) {
    const float* node_emb = (const float*)d_in[0];
    const float* rel_emb  = (const float*)d_in[1];
    const int*   src      = (const int*)d_in[2];
    const int*   dst      = (const int*)d_in[3];
    float* out = (float*)d_out;

    const int n_edges = in_sizes[2];       // E = 500000
    const int waves_per_block = 256 / 64;  // 4 edges per block
    const int blocks = (n_edges + waves_per_block - 1) / waves_per_block;

    simple_score_kernel<<<blocks, 256, 0, stream>>>(
        node_emb, rel_emb, src, dst, out, n_edges);
}